// Round 3
// baseline (2189.852 us; speedup 1.0000x reference)
//
#include <hip/hip_runtime.h>
#include <math.h>

#define HID 128
#define NRAYS 4096
#define TPB 128   // points per MLP block (2 per lane, 4 waves of 64)

__device__ __forceinline__ float sp_f(float x){        // jax.nn.softplus, stable
  return fmaxf(x, 0.0f) + log1pf(expf(-fabsf(x)));
}
__device__ __forceinline__ float sg_f(float x){        // sigmoid
  return 1.0f / (1.0f + expf(-x));
}
// force pointer into VGPRs -> guarantees vector (VMEM) loads, vmcnt-pipelined
__device__ __forceinline__ const float4* vptr(const float4* p){
  asm volatile("" : "+v"(p));
  return p;
}
__device__ __forceinline__ void ldrow(float4 (&w)[8], const float4* __restrict__ base){
  #pragma unroll
  for (int t = 0; t < 8; t++) w[t] = base[t];
}
__device__ __forceinline__ void fma32x2(float (&acc)[32][2], const float4 (&w)[8],
                                        float ha, float hb){
  #pragma unroll
  for (int j = 0; j < 8; j++){
    const float wc[4] = {w[j].x, w[j].y, w[j].z, w[j].w};
    #pragma unroll
    for (int c = 0; c < 4; c++){
      acc[j*4+c][0] = fmaf(ha, wc[c], acc[j*4+c][0]);
      acc[j*4+c][1] = fmaf(hb, wc[c], acc[j*4+c][1]);
    }
  }
}

// ---------------------------------------------------------------- transpose W2
__global__ void k_transpose(const float* __restrict__ W2, float* __restrict__ W2T){
  int idx = blockIdx.x*256 + threadIdx.x;
  if (idx < HID*HID){
    int k = idx >> 7, n = idx & 127;
    W2T[n*HID + k] = W2[k*HID + n];
  }
}

// ---------------------------------------------------------------- initial z + pts
__global__ void k_init(const float* __restrict__ rays_o, const float* __restrict__ rays_d,
                       const float* __restrict__ nearv, const float* __restrict__ farv,
                       float* __restrict__ z_buf, float* __restrict__ pts){
  int idx = blockIdx.x*256 + threadIdx.x;
  if (idx >= NRAYS*64) return;
  int ray = idx >> 6, j = idx & 63;
  float nr = nearv[ray];
  float z = nr + (farv[ray] - nr) * ((float)j / 63.0f);
  z_buf[ray*128 + j] = z;
  pts[idx*3+0] = rays_o[ray*3+0] + rays_d[ray*3+0]*z;
  pts[idx*3+1] = rays_o[ray*3+1] + rays_d[ray*3+1]*z;
  pts[idx*3+2] = rays_o[ray*3+2] + rays_d[ray*3+2]*z;
}

// ---------------------------------------------------------------- MLP forward
// 4 waves; wave w owns neurons [32w,32w+32); lane owns points l and l+64.
// W2 rows streamed through a VGPR ping-pong (vector loads, explicit prefetch).
__global__ __launch_bounds__(256, 2) void k_mlp_fwd(
    const float* __restrict__ pts,
    const float* __restrict__ W1, const float* __restrict__ b1,
    const float* __restrict__ W2, const float* __restrict__ b2,
    const float* __restrict__ W3, const float* __restrict__ b3,
    float* __restrict__ sdf_out){
  __shared__ float sH[HID*TPB];   // h1 [k][p]  (64 KB)
  __shared__ float sRed[4*TPB];
  const int tid = threadIdx.x;
  const int l   = tid & 63;
  const int wv  = __builtin_amdgcn_readfirstlane(tid >> 6);
  const int n0  = wv * 32;
  const int q0  = blockIdx.x * TPB;
  const int pA  = l, pB = l + 64;
  const float x0a = pts[(q0+pA)*3+0], x1a = pts[(q0+pA)*3+1], x2a = pts[(q0+pA)*3+2];
  const float x0b = pts[(q0+pB)*3+0], x1b = pts[(q0+pB)*3+1], x2b = pts[(q0+pB)*3+2];
  // layer 1: wave's 32 rows for its 2 points/lane
  #pragma unroll
  for (int kk = 0; kk < 32; kk++){
    int k = n0 + kk;
    float w1a = W1[k], w1b = W1[HID+k], w1c = W1[2*HID+k], bb = b1[k];
    sH[k*TPB+pA] = sp_f(fmaf(x2a, w1c, fmaf(x1a, w1b, fmaf(x0a, w1a, bb))));
    sH[k*TPB+pB] = sp_f(fmaf(x2b, w1c, fmaf(x1b, w1b, fmaf(x0b, w1a, bb))));
  }
  __syncthreads();
  // layer 2: ping-pong weight rows
  float acc[32][2];
  #pragma unroll
  for (int j = 0; j < 32; j++){ float b = b2[n0+j]; acc[j][0] = b; acc[j][1] = b; }
  const float4* w2v = reinterpret_cast<const float4*>(W2 + n0);  // row k at +k*32
  float4 wA[8], wB[8];
  ldrow(wA, vptr(w2v));
  for (int k = 0; k < HID; k += 2){
    ldrow(wB, vptr(w2v + (k+1)*32));
    fma32x2(acc, wA, sH[k*TPB+pA], sH[k*TPB+pB]);
    ldrow(wA, vptr(w2v + ((k+2)&127)*32));
    fma32x2(acc, wB, sH[(k+1)*TPB+pA], sH[(k+1)*TPB+pB]);
  }
  // layer 3 partials
  float partA = 0.0f, partB = 0.0f;
  #pragma unroll
  for (int j = 0; j < 32; j++){
    float w3 = W3[n0+j];
    partA += sp_f(acc[j][0]) * w3;
    partB += sp_f(acc[j][1]) * w3;
  }
  sRed[wv*TPB + pA] = partA;
  sRed[wv*TPB + pB] = partB;
  __syncthreads();
  if (tid < TPB)
    sdf_out[q0+tid] = b3[0] + sRed[tid] + sRed[TPB+tid] + sRed[2*TPB+tid] + sRed[3*TPB+tid];
}

// ---------------------------------------------------------------- scatters
__global__ void k_scatter_init(const float* __restrict__ sdf_tmp, float* __restrict__ sdf_buf){
  int idx = blockIdx.x*256 + threadIdx.x;
  if (idx >= NRAYS*64) return;
  sdf_buf[(idx >> 6)*128 + (idx & 63)] = sdf_tmp[idx];
}
__global__ void k_scatter_new(const float* __restrict__ sdf_tmp, const int* __restrict__ slots,
                              float* __restrict__ sdf_buf){
  int idx = blockIdx.x*256 + threadIdx.x;
  if (idx >= NRAYS*16) return;
  sdf_buf[(idx >> 4)*128 + slots[idx]] = sdf_tmp[idx];
}

// ---------------------------------------------------------------- upsample (one wave per ray)
__global__ __launch_bounds__(64) void k_upsample(
      const float* __restrict__ rays_o, const float* __restrict__ rays_d,
      float* __restrict__ z_buf, float* __restrict__ sdf_buf,
      float* __restrict__ pts_new, int* __restrict__ slots,
      int S, float inv_s, int last){
  __shared__ float z[128], sd[128], rad[128], cosv[128], alf[128], wv[128], cdf[129], nz[16];
  __shared__ int slt[16];
  const int ray = blockIdx.x;
  const int l   = threadIdx.x;
  const float ox = rays_o[ray*3], oy = rays_o[ray*3+1], oz = rays_o[ray*3+2];
  const float dx = rays_d[ray*3], dy = rays_d[ray*3+1], dz = rays_d[ray*3+2];
  for (int j = l; j < S; j += 64){
    float zz = z_buf[ray*128+j];
    z[j]  = zz;
    sd[j] = sdf_buf[ray*128+j];
    float px = ox+dx*zz, py = oy+dy*zz, pz = oz+dz*zz;
    rad[j] = sqrtf(px*px + py*py + pz*pz);
  }
  __syncthreads();
  for (int j = l; j < S-1; j += 64)
    cosv[j] = (sd[j+1]-sd[j]) / (z[j+1]-z[j] + 1e-5f);
  __syncthreads();
  for (int j = l; j < S-1; j += 64){
    float cv = fminf((j > 0) ? cosv[j-1] : 0.0f, cosv[j]);
    cv = fminf(fmaxf(cv, -1000.0f), 0.0f);
    float inside = (rad[j] < 1.0f || rad[j+1] < 1.0f) ? 1.0f : 0.0f;
    cv *= inside;
    float mid  = 0.5f*(sd[j]+sd[j+1]);
    float dist = z[j+1]-z[j];
    float e = sg_f((mid - cv*dist*0.5f)*inv_s);
    float f = sg_f((mid + cv*dist*0.5f)*inv_s);
    alf[j] = (e - f + 1e-5f) / (e + 1e-5f);
  }
  __syncthreads();
  if (l == 0){
    float T = 1.0f, wsum = 0.0f;
    for (int j = 0; j < S-1; j++){
      float w = alf[j]*T + 1e-5f;   // weights = alpha*trans + 1e-5
      wv[j] = w; wsum += w;
      T *= (1.0f - alf[j] + 1e-7f);
    }
    cdf[0] = 0.0f;
    float c = 0.0f;
    for (int j = 0; j < S-1; j++){ c += wv[j]/wsum; cdf[j+1] = c; }
  }
  __syncthreads();
  if (l < 16){
    float u = 0.03125f + 0.0625f*(float)l;   // linspace(1/32, 31/32, 16)
    int idx = 0;
    while (idx < S && cdf[idx] <= u) idx++;  // searchsorted side='right'
    int below = idx - 1; if (below < 0) below = 0;
    int above = (idx < S-1) ? idx : (S-1);
    float cb = cdf[below], ca = cdf[above];
    float den = ca - cb; if (den < 1e-5f) den = 1.0f;
    float t = (u - cb) / den;
    nz[l] = z[below] + t*(z[above] - z[below]);
  }
  __syncthreads();
  if (l == 0){
    // stable in-place merge from the back (old-before-new on ties)
    int i = S-1, j = 15;
    for (int dst = S+15; dst >= 0; --dst){
      bool takeOld = (j < 0) || (i >= 0 && z[i] > nz[j]);
      if (takeOld){ z[dst] = z[i]; sd[dst] = sd[i]; i--; }
      else        { z[dst] = nz[j]; slt[j] = dst; j--; }
    }
  }
  __syncthreads();
  for (int j = l; j < S+16; j += 64){
    z_buf[ray*128+j]  = z[j];
    sdf_buf[ray*128+j] = sd[j];
  }
  if (!last && l < 16){
    slots[ray*16+l] = slt[l];
    float zz = nz[l];
    pts_new[(ray*16+l)*3+0] = ox + dx*zz;
    pts_new[(ray*16+l)*3+1] = oy + dy*zz;
    pts_new[(ray*16+l)*3+2] = oz + dz*zz;
  }
}

// ---------------------------------------------------------------- final mid-point pts
__global__ void k_prep(const float* __restrict__ rays_o, const float* __restrict__ rays_d,
                       const float* __restrict__ z_buf, float* __restrict__ pts){
  int idx = blockIdx.x*256 + threadIdx.x;
  if (idx >= NRAYS*128) return;
  int ray = idx >> 7, s = idx & 127;
  float z = z_buf[idx];
  float d = (s < 127) ? (z_buf[idx+1] - z) : 0.03125f;   // SAMPLE_DIST = 2/64
  float mid = z + 0.5f*d;
  pts[idx*3+0] = rays_o[ray*3+0] + rays_d[ray*3+0]*mid;
  pts[idx*3+1] = rays_o[ray*3+1] + rays_d[ray*3+1]*mid;
  pts[idx*3+2] = rays_o[ray*3+2] + rays_d[ray*3+2]*mid;
}

// ---------------------------------------------------------------- MLP forward + input-gradient
// Same tiling as k_mlp_fwd. Phase A fwd (W2 rows), phase C bwd (W2T rows); sH
// swaps h1 -> g2 between barriers; pre1 recomputed from x for the grad epilogue.
__global__ __launch_bounds__(256, 2) void k_mlp_fwdbwd(
    const float* __restrict__ pts,
    const float* __restrict__ W1, const float* __restrict__ b1,
    const float* __restrict__ W2, const float* __restrict__ b2,
    const float* __restrict__ W3, const float* __restrict__ b3,
    const float* __restrict__ W2T,
    float* __restrict__ sdf_out, float* __restrict__ grad_out){
  __shared__ float sH[HID*TPB];   // h1 in phase A, g2 in phase C (64 KB)
  __shared__ float sRed[4*TPB];
  __shared__ float sGx[4*TPB], sGy[4*TPB], sGz[4*TPB];
  const int tid = threadIdx.x;
  const int l   = tid & 63;
  const int wv  = __builtin_amdgcn_readfirstlane(tid >> 6);
  const int n0  = wv * 32;
  const int q0  = blockIdx.x * TPB;
  const int pA  = l, pB = l + 64;
  const float x0a = pts[(q0+pA)*3+0], x1a = pts[(q0+pA)*3+1], x2a = pts[(q0+pA)*3+2];
  const float x0b = pts[(q0+pB)*3+0], x1b = pts[(q0+pB)*3+1], x2b = pts[(q0+pB)*3+2];
  // layer 1
  #pragma unroll
  for (int kk = 0; kk < 32; kk++){
    int k = n0 + kk;
    float w1a = W1[k], w1b = W1[HID+k], w1c = W1[2*HID+k], bb = b1[k];
    sH[k*TPB+pA] = sp_f(fmaf(x2a, w1c, fmaf(x1a, w1b, fmaf(x0a, w1a, bb))));
    sH[k*TPB+pB] = sp_f(fmaf(x2b, w1c, fmaf(x1b, w1b, fmaf(x0b, w1a, bb))));
  }
  __syncthreads();
  // phase A: layer 2 forward
  float acc[32][2];
  #pragma unroll
  for (int j = 0; j < 32; j++){ float b = b2[n0+j]; acc[j][0] = b; acc[j][1] = b; }
  {
    const float4* w2v = reinterpret_cast<const float4*>(W2 + n0);
    float4 wA[8], wB[8];
    ldrow(wA, vptr(w2v));
    for (int k = 0; k < HID; k += 2){
      ldrow(wB, vptr(w2v + (k+1)*32));
      fma32x2(acc, wA, sH[k*TPB+pA], sH[k*TPB+pB]);
      ldrow(wA, vptr(w2v + ((k+2)&127)*32));
      fma32x2(acc, wB, sH[(k+1)*TPB+pA], sH[(k+1)*TPB+pB]);
    }
  }
  // sdf partials
  {
    float partA = 0.0f, partB = 0.0f;
    #pragma unroll
    for (int j = 0; j < 32; j++){
      float w3 = W3[n0+j];
      partA += sp_f(acc[j][0]) * w3;
      partB += sp_f(acc[j][1]) * w3;
    }
    sRed[wv*TPB + pA] = partA;
    sRed[wv*TPB + pB] = partB;
  }
  __syncthreads();   // all waves done reading h1
  // overwrite sH with g2 = sigmoid(pre2) * W3
  #pragma unroll
  for (int j = 0; j < 32; j++){
    float w3 = W3[n0+j];
    sH[(n0+j)*TPB + pA] = sg_f(acc[j][0]) * w3;
    sH[(n0+j)*TPB + pB] = sg_f(acc[j][1]) * w3;
  }
  __syncthreads();
  // phase C: dh1[k] = sum_n g2[n] * W2T[n][k]
  float accD[32][2];
  #pragma unroll
  for (int j = 0; j < 32; j++){ accD[j][0] = 0.0f; accD[j][1] = 0.0f; }
  {
    const float4* w2tv = reinterpret_cast<const float4*>(W2T + n0);
    float4 wA[8], wB[8];
    ldrow(wA, vptr(w2tv));
    for (int n = 0; n < HID; n += 2){
      ldrow(wB, vptr(w2tv + (n+1)*32));
      fma32x2(accD, wA, sH[n*TPB+pA], sH[n*TPB+pB]);
      ldrow(wA, vptr(w2tv + ((n+2)&127)*32));
      fma32x2(accD, wB, sH[(n+1)*TPB+pA], sH[(n+1)*TPB+pB]);
    }
  }
  // grad partials: dp1 = dh1 * sigmoid(pre1); grad = W1 @ dp1
  {
    float gxa = 0.f, gya = 0.f, gza = 0.f;
    float gxb = 0.f, gyb = 0.f, gzb = 0.f;
    #pragma unroll
    for (int j = 0; j < 32; j++){
      int k = n0 + j;
      float w1a = W1[k], w1b = W1[HID+k], w1c = W1[2*HID+k], bb = b1[k];
      float pre1a = fmaf(x2a, w1c, fmaf(x1a, w1b, fmaf(x0a, w1a, bb)));
      float pre1b = fmaf(x2b, w1c, fmaf(x1b, w1b, fmaf(x0b, w1a, bb)));
      float da = accD[j][0] * sg_f(pre1a);
      float db = accD[j][1] * sg_f(pre1b);
      gxa = fmaf(w1a, da, gxa); gya = fmaf(w1b, da, gya); gza = fmaf(w1c, da, gza);
      gxb = fmaf(w1a, db, gxb); gyb = fmaf(w1b, db, gyb); gzb = fmaf(w1c, db, gzb);
    }
    sGx[wv*TPB + pA] = gxa; sGy[wv*TPB + pA] = gya; sGz[wv*TPB + pA] = gza;
    sGx[wv*TPB + pB] = gxb; sGy[wv*TPB + pB] = gyb; sGz[wv*TPB + pB] = gzb;
  }
  __syncthreads();
  if (tid < TPB){
    sdf_out[q0+tid] = b3[0] + sRed[tid] + sRed[TPB+tid] + sRed[2*TPB+tid] + sRed[3*TPB+tid];
    float gx = sGx[tid] + sGx[TPB+tid] + sGx[2*TPB+tid] + sGx[3*TPB+tid];
    float gy = sGy[tid] + sGy[TPB+tid] + sGy[2*TPB+tid] + sGy[3*TPB+tid];
    float gz = sGz[tid] + sGz[TPB+tid] + sGz[2*TPB+tid] + sGz[3*TPB+tid];
    grad_out[(q0+tid)*3+0] = gx;
    grad_out[(q0+tid)*3+1] = gy;
    grad_out[(q0+tid)*3+2] = gz;
  }
}

// ---------------------------------------------------------------- render (one thread per ray)
__global__ void k_render(const float* __restrict__ z_buf, const float* __restrict__ sdf_mid,
                         const float* __restrict__ rays_d, const float* __restrict__ grad,
                         const float* __restrict__ variance, float* __restrict__ depth_out){
  int ray = blockIdx.x*64 + threadIdx.x;
  if (ray >= NRAYS) return;
  float inv_s = expf(10.0f * variance[0]);
  inv_s = fminf(fmaxf(inv_s, 1e-6f), 1e6f);
  const float dx = rays_d[ray*3], dy = rays_d[ray*3+1], dz = rays_d[ray*3+2];
  float T = 1.0f, depth = 0.0f;
  float zc = z_buf[ray*128];
  for (int s = 0; s < 128; s++){
    int idx = ray*128 + s;
    float zn = (s < 127) ? z_buf[idx+1] : zc;
    float d  = (s < 127) ? (zn - zc) : 0.03125f;
    float sdf = sdf_mid[idx];
    float gx = grad[idx*3], gy = grad[idx*3+1], gz = grad[idx*3+2];
    float tc = dx*gx + dy*gy + dz*gz;
    float ic = -fmaxf(0.5f - 0.5f*tc, 0.0f);     // COS_ANNEAL_RATIO = 0
    float e = sg_f((sdf - ic*d*0.5f)*inv_s);
    float f = sg_f((sdf + ic*d*0.5f)*inv_s);
    float a = (e - f + 1e-5f) / (e + 1e-5f);
    a = fminf(fmaxf(a, 0.0f), 1.0f);
    depth += a*T*zc;
    T *= (1.0f - a + 1e-7f);
    zc = zn;
  }
  depth_out[ray] = depth;
}

// ---------------------------------------------------------------- launcher
extern "C" void kernel_launch(void* const* d_in, const int* in_sizes, int n_in,
                              void* d_out, int out_size, void* d_ws, size_t ws_size,
                              hipStream_t stream){
  (void)in_sizes; (void)n_in; (void)out_size; (void)ws_size;
  const float* rays_o = (const float*)d_in[0];
  const float* rays_d = (const float*)d_in[1];
  const float* nearv  = (const float*)d_in[2];
  const float* farv   = (const float*)d_in[3];
  const float* W1 = (const float*)d_in[4];
  const float* b1 = (const float*)d_in[5];
  const float* W2 = (const float*)d_in[6];
  const float* b2 = (const float*)d_in[7];
  const float* W3 = (const float*)d_in[8];
  const float* b3 = (const float*)d_in[9];
  const float* variance = (const float*)d_in[10];

  float* ws      = (float*)d_ws;
  float* z_buf   = ws;                    // 4096*128
  float* sdf_buf = ws + 524288;           // 4096*128
  float* sdf_tmp = ws + 1048576;          // up to 524288
  float* W2T     = ws + 1572864;          // 16384
  int*   slots   = (int*)(ws + 1589248);  // 4096*16 ints

  float* out       = (float*)d_out;
  float* depth_out = out;
  float* grad_out  = out + NRAYS;         // 524288*3 floats
  float* pts       = grad_out;            // alias: pts staging lives in the grad region

  k_transpose<<<dim3(64), dim3(256), 0, stream>>>(W2, W2T);
  k_init<<<dim3(1024), dim3(256), 0, stream>>>(rays_o, rays_d, nearv, farv, z_buf, pts);
  k_mlp_fwd<<<dim3(2048), dim3(256), 0, stream>>>(pts, W1,b1,W2,b2,W3,b3, sdf_tmp);
  k_scatter_init<<<dim3(1024), dim3(256), 0, stream>>>(sdf_tmp, sdf_buf);

  for (int i = 0; i < 4; i++){
    int S = 64 + 16*i;
    float inv_s = (float)(64 << i);
    int last = (i == 3) ? 1 : 0;
    k_upsample<<<dim3(4096), dim3(64), 0, stream>>>(rays_o, rays_d, z_buf, sdf_buf,
                                                    pts, slots, S, inv_s, last);
    if (!last){
      k_mlp_fwd<<<dim3(512), dim3(256), 0, stream>>>(pts, W1,b1,W2,b2,W3,b3, sdf_tmp);
      k_scatter_new<<<dim3(256), dim3(256), 0, stream>>>(sdf_tmp, slots, sdf_buf);
    }
  }

  k_prep<<<dim3(2048), dim3(256), 0, stream>>>(rays_o, rays_d, z_buf, pts);
  k_mlp_fwdbwd<<<dim3(4096), dim3(256), 0, stream>>>(pts, W1,b1,W2,b2,W3,b3, W2T,
                                                     sdf_tmp, grad_out);
  k_render<<<dim3(64), dim3(64), 0, stream>>>(z_buf, sdf_tmp, rays_d, grad_out,
                                              variance, depth_out);
}